// Round 9
// baseline (187.245 us; speedup 1.0000x reference)
//
#include <hip/hip_runtime.h>
#include <hip/hip_bf16.h>

// MHA forward. Inputs/output fp32; internal bf16 MFMA, fp32 accumulate.
// B=2 T=2048 C=1024 H=16 D=64. M=4096.
// ws (32 MB): qbuf[0,8M) bf16[4096][1024] (Q pre-scaled by 0.125*log2e; ctx overwrites)
//             kbuf[8,16M) | vt[16,24M) | woutT[24,26M) | wqkvT[26,32.3M)
// d_out as scratch until GEMM2: xb bf16 at +0.

typedef __attribute__((ext_vector_type(8)))  short short8;    // 8 bf16
typedef __attribute__((ext_vector_type(4)))  float floatx4;   // 4 fp32
typedef __attribute__((ext_vector_type(16))) float floatx16;  // 16 fp32 (32x32 acc)

__device__ inline ushort f2bf(float f) {
    union { __hip_bfloat16 h; ushort u; } c; c.h = __float2bfloat16(f); return c.u;
}

// pack two fp32 -> {lo:bf16(a), hi:bf16(b)} in one VALU op (RNE)
__device__ inline uint cvt_pk_bf16(float a, float b) {
    uint r;
    asm("v_cvt_pk_bf16_f32 %0, %1, %2" : "=v"(r) : "v"(a), "v"(b));
    return r;
}

// async global->LDS, 16B/lane; LDS dest = wave-uniform base + lane*16.
__device__ inline void gld16(const ushort* g, ushort* l) {
    __builtin_amdgcn_global_load_lds(
        (__attribute__((address_space(1))) void*)(g),
        (__attribute__((address_space(3))) void*)(l), 16, 0, 0);
}

// ---------------- fused prep: cvt_x + transpose W_qkv + transpose W_out ----------------
__device__ inline void tile_transpose(const float* __restrict__ src, ushort* __restrict__ dst,
                                      int R, int C, int rt, int ct, int t, ushort* L)
{
    const int row = t >> 2, cc = (t & 3) * 16;
    const float* sp = src + (long)(rt * 64 + row) * C + ct * 64 + cc;
    ushort tmp[16];
    #pragma unroll
    for (int i = 0; i < 4; i++) {
        float4 v = *(const float4*)(sp + i * 4);
        tmp[i*4+0]=f2bf(v.x); tmp[i*4+1]=f2bf(v.y); tmp[i*4+2]=f2bf(v.z); tmp[i*4+3]=f2bf(v.w);
    }
    *(uint4*)&L[row * 72 + cc]     = *(uint4*)&tmp[0];
    *(uint4*)&L[row * 72 + cc + 8] = *(uint4*)&tmp[8];
    __syncthreads();
    const int c = t >> 2, rc = (t & 3) * 16;
    ushort o[16];
    #pragma unroll
    for (int j = 0; j < 16; j++) o[j] = L[(rc + j) * 72 + c];
    ushort* dp = dst + (long)(ct * 64 + c) * R + rt * 64 + rc;
    *(uint4*)dp       = *(uint4*)&o[0];
    *(uint4*)(dp + 8) = *(uint4*)&o[8];
}

__global__ __launch_bounds__(256) void prep_kernel(
    const float* __restrict__ x, const float* __restrict__ Wqkv, const float* __restrict__ Wout,
    ushort* __restrict__ xb, ushort* __restrict__ wqkvT, ushort* __restrict__ woutT)
{
    __shared__ __align__(16) ushort L[64 * 72];
    const int bid = blockIdx.x, t = threadIdx.x;
    if (bid < 2048) {                                   // cvt_x
        long i = ((long)bid * 256 + t) * 8;
        float4 a = *(const float4*)(x + i);
        float4 b = *(const float4*)(x + i + 4);
        ushort tmp[8] = { f2bf(a.x), f2bf(a.y), f2bf(a.z), f2bf(a.w),
                          f2bf(b.x), f2bf(b.y), f2bf(b.z), f2bf(b.w) };
        *(uint4*)(xb + i) = *(uint4*)tmp;
    } else if (bid < 2048 + 768) {                      // W_qkv^T: 16 x 48 tiles
        int idx = bid - 2048;
        tile_transpose(Wqkv, wqkvT, 1024, 3072, idx & 15, idx >> 4, t, L);
    } else {                                            // W_out^T: 16 x 16 tiles
        int idx = bid - 2048 - 768;
        tile_transpose(Wout, woutT, 1024, 1024, idx & 15, idx >> 4, t, L);
    }
}

// ---------------- GEMM1: xb × wqkvT^T + b -> qbuf/kbuf/vt ----------------
// 2-phase pipelined staging, BK=32: the two 16 KB LDS halves are ping-pong
// phase buffers; stage(k+1 -> alt) issues BEFORE compute(k), so the glds
// loads fly under the 16 MFMAs instead of being drained cold at the barrier.
// Barrier count per K unchanged (1 per 32-K); LDS 32 KB; occupancy 3/CU.
// K-step order identical to the old kernel -> bit-identical accumulation.
// XCD supertile: 1-D grid 768, id&7 = XCD owns a 12x8 block supertile (bijective).
#define QSCALE 0.18033688011112042f   // (1/8) * log2(e), folded into Q

__global__ __launch_bounds__(256, 3) void qkv_gemm_kernel(
    const ushort* __restrict__ A, const ushort* __restrict__ Bt,
    const float* __restrict__ bias,
    ushort* __restrict__ qbuf, ushort* __restrict__ kbuf, ushort* __restrict__ vtG)
{
    __shared__ __align__(16) ushort SMEM[16384];   // phase p at p*8192: A[128][32] | B[128][32]

    const int t = threadIdx.x;
    const int w = t >> 6, lane = t & 63;
    const int r = lane & 15, qq = lane >> 4;
    const int wm = w >> 1, wn = w & 1;

    const int id = blockIdx.x;
    const int xcd = id & 7, cidx = id >> 3;        // 96 blocks per XCD
    const int lx = cidx % 12, ly = cidx / 12;      // 12 x 8 supertile
    const int bx = (xcd & 1) * 12 + lx;            // 0..23
    const int by = (xcd >> 1) * 8 + ly;            // 0..31
    const int rowBase = by * 128, colBase = bx * 128;

    // staging: wave w covers rows [w*32, w*32+32) of A and B (2 gld16 each)
    const int s_row = lane >> 2, s_k = (lane & 3) * 8;
    const ushort* aS = A  + (long)(rowBase + w * 32 + s_row) * 1024 + s_k;
    const ushort* bS = Bt + (long)(colBase + w * 32 + s_row) * 1024 + s_k;

    floatx4 acc[4][4] = {};

    // prologue: stage k-step 0 into phase 0
    gld16(aS,             SMEM + w * 1024);
    gld16(aS + 16 * 1024, SMEM + w * 1024 + 512);
    gld16(bS,             SMEM + 4096 + w * 1024);
    gld16(bS + 16 * 1024, SMEM + 4096 + w * 1024 + 512);
    __syncthreads();

    #pragma unroll 2
    for (int k = 0; k < 32; k++) {
        ushort* cur = SMEM + (k & 1) * 8192;
        if (k < 31) {               // stage k+1 into the alternate phase buffer
            ushort* nxt = SMEM + ((k + 1) & 1) * 8192;
            const int ko = (k + 1) * 32;
            gld16(aS + ko,             nxt + w * 1024);
            gld16(aS + ko + 16 * 1024, nxt + w * 1024 + 512);
            gld16(bS + ko,             nxt + 4096 + w * 1024);
            gld16(bS + ko + 16 * 1024, nxt + 4096 + w * 1024 + 512);
        }
        short8 af[4], bf4[4];
        #pragma unroll
        for (int tm = 0; tm < 4; tm++) af[tm]  = *(const short8*)&cur[(wm * 64 + tm * 16 + r) * 32 + qq * 8];
        #pragma unroll
        for (int tn = 0; tn < 4; tn++) bf4[tn] = *(const short8*)&cur[4096 + (wn * 64 + tn * 16 + r) * 32 + qq * 8];
        #pragma unroll
        for (int tm = 0; tm < 4; tm++)
            #pragma unroll
            for (int tn = 0; tn < 4; tn++)
                acc[tm][tn] = __builtin_amdgcn_mfma_f32_16x16x32_bf16(af[tm], bf4[tn], acc[tm][tn], 0, 0, 0);
        __syncthreads();            // publishes stage(k+1); WAR on cur safe (next write is k+2)
    }

    if (colBase < 2048) {
        // Q / K columns: row-major coalesced store (Q pre-scaled by QSCALE)
        #pragma unroll
        for (int tn = 0; tn < 4; tn++) {
            int col = colBase + wn * 64 + tn * 16 + r;
            float bvv = bias[col];
            #pragma unroll
            for (int tm = 0; tm < 4; tm++) {
                #pragma unroll
                for (int reg = 0; reg < 4; reg++) {
                    int row = rowBase + wm * 64 + tm * 16 + qq * 4 + reg;
                    float val = acc[tm][tn][reg] + bvv;
                    if (colBase < 1024) qbuf[(long)row * 1024 + col]        = f2bf(val * QSCALE);
                    else                kbuf[(long)row * 1024 + col - 1024] = f2bf(val);
                }
            }
        }
    } else {
        // V columns: transpose 128(t) x 64(d) per head-half through LDS -> vt[bh*64+d][t]
        ushort* L = SMEM;   // 64 x 136 scratch (8704 ushorts <= 16384)
        #pragma unroll
        for (int hh = 0; hh < 2; hh++) {
            __syncthreads();
            if (wn == hh) {
                #pragma unroll
                for (int tn = 0; tn < 4; tn++) {
                    int vc = tn * 16 + r;
                    float bvv = bias[colBase + wn * 64 + vc];
                    #pragma unroll
                    for (int tm = 0; tm < 4; tm++) {
                        int row0 = wm * 64 + tm * 16 + qq * 4;
                        ushort q4[4] = { f2bf(acc[tm][tn][0] + bvv), f2bf(acc[tm][tn][1] + bvv),
                                         f2bf(acc[tm][tn][2] + bvv), f2bf(acc[tm][tn][3] + bvv) };
                        *(uint2*)&L[vc * 136 + row0] = *(uint2*)q4;
                    }
                }
            }
            __syncthreads();
            int d = t >> 2, tq = (t & 3) * 32;
            int h_loc = ((colBase - 2048) >> 6) + hh;
            long vtrow = (long)((rowBase >> 11) * 16 + h_loc) * 64 + d;
            ushort* dst = vtG + vtrow * 2048 + (rowBase & 2047) + tq;
            #pragma unroll
            for (int i = 0; i < 4; i++)
                *(uint4*)(dst + 8 * i) = *(uint4*)&L[d * 136 + tq + 8 * i];
        }
    }
}

// ---------------- GEMM2: ctx × woutT^T + b -> fp32 out ----------------
// Same 2-phase BK=32 pipeline (A 128x32 + B 64x32 per phase = 12 KB, x2 = 24 KB).
// XCD supertile: 1-D grid 512, id&7 = XCD owns an 8x8 block supertile (bijective).
__global__ __launch_bounds__(256) void out_gemm_kernel(
    const ushort* __restrict__ A, const ushort* __restrict__ Bt,
    const float* __restrict__ bias, float* __restrict__ out)
{
    __shared__ __align__(16) ushort SMEM[12288];   // phase p at p*6144: A[128][32] | B[64][32]

    const int t = threadIdx.x;
    const int w = t >> 6, lane = t & 63;
    const int r = lane & 15, qq = lane >> 4;
    const int wm = w >> 1, wn = w & 1;

    const int id = blockIdx.x;
    const int xcd = id & 7, cidx = id >> 3;        // 64 blocks per XCD
    const int bx = (xcd & 1) * 8 + (cidx & 7);     // 0..15
    const int by = (xcd >> 1) * 8 + (cidx >> 3);   // 0..31
    const int rowBase = by * 128, colBase = bx * 64;

    const int s_row = lane >> 2, s_k = (lane & 3) * 8;
    const ushort* aS = A  + (long)(rowBase + w * 32 + s_row) * 1024 + s_k;
    const ushort* bS = Bt + (long)(colBase + w * 16 + s_row) * 1024 + s_k;

    floatx4 acc[4][2] = {};

    // prologue: stage k-step 0 into phase 0
    gld16(aS,             SMEM + w * 1024);
    gld16(aS + 16 * 1024, SMEM + w * 1024 + 512);
    gld16(bS,             SMEM + 4096 + w * 512);
    __syncthreads();

    #pragma unroll 2
    for (int k = 0; k < 32; k++) {
        ushort* cur = SMEM + (k & 1) * 6144;
        if (k < 31) {
            ushort* nxt = SMEM + ((k + 1) & 1) * 6144;
            const int ko = (k + 1) * 32;
            gld16(aS + ko,             nxt + w * 1024);
            gld16(aS + ko + 16 * 1024, nxt + w * 1024 + 512);
            gld16(bS + ko,             nxt + 4096 + w * 512);
        }
        short8 af[4], bf2[2];
        #pragma unroll
        for (int tm = 0; tm < 4; tm++) af[tm]  = *(const short8*)&cur[(wm * 64 + tm * 16 + r) * 32 + qq * 8];
        #pragma unroll
        for (int tn = 0; tn < 2; tn++) bf2[tn] = *(const short8*)&cur[4096 + (wn * 32 + tn * 16 + r) * 32 + qq * 8];
        #pragma unroll
        for (int tm = 0; tm < 4; tm++)
            #pragma unroll
            for (int tn = 0; tn < 2; tn++)
                acc[tm][tn] = __builtin_amdgcn_mfma_f32_16x16x32_bf16(af[tm], bf2[tn], acc[tm][tn], 0, 0, 0);
        __syncthreads();
    }

    #pragma unroll
    for (int tn = 0; tn < 2; tn++) {
        int col = colBase + wn * 32 + tn * 16 + r;
        float bvv = bias[col];
        #pragma unroll
        for (int tm = 0; tm < 4; tm++) {
            #pragma unroll
            for (int reg = 0; reg < 4; reg++) {
                int row = rowBase + wm * 64 + tm * 16 + qq * 4 + reg;
                out[(long)row * 1024 + col] = acc[tm][tn][reg] + bvv;
            }
        }
    }
}

// ---------------- MFMA flash attention, 32x32x16, transposed ----------------
// R8-passing structure, VERBATIM: 512-thread blocks, 8 waves; waves 0-3 (h2=0)
// process KV tiles 0..15, waves 4-7 (h2=1) tiles 16..31; each half
// double-buffers its own K/V LDS. QK's ds_read+MFMA cluster issues FIRST at
// barrier-exit; staging ds_writes drain under it. Row-sum via ones-A MFMA.
// Combine: ctx = (O0+O1)/(l0+l1), exact (plain exp2 sums, no running max).
__global__ __launch_bounds__(512, 4) void attn_kernel(
    ushort* __restrict__ qbuf, const ushort* __restrict__ kbuf,
    const ushort* __restrict__ vt)
{
    __shared__ __align__(16) ushort SM[2][2][2][64 * 72];   // [half][buf][K/V] = 73.7 KB

    const int t = threadIdx.x;
    const int w = t >> 6, lane = t & 63;
    const int m32 = lane & 31, hi = lane >> 5;
    const int h2 = w >> 2, wq = w & 3;          // KV-half, q-subtile

    // XCD-aware decode: id&7 = XCD gets 4 whole (b,h) groups -> K/V L2-resident.
    const int id = blockIdx.x;
    const int j = id >> 3;
    const int bh = (id & 7) * 4 + (j >> 4);     // 0..31
    const int qt = j & 15;                      // 0..15 (BQ = 128; wave owns 32 q)
    const int b = bh >> 4, h = bh & 15;
    const long qrow = (long)(b * 2048 + qt * 128 + wq * 32 + m32);

    short8 qfrag[4];
    #pragma unroll
    for (int dc = 0; dc < 4; dc++)
        qfrag[dc] = *(const short8*)(qbuf + qrow * 1024 + h * 64 + dc * 16 + hi * 8);

    short8 vones;
    #pragma unroll
    for (int i = 0; i < 8; i++) vones[i] = (short)0x3F80;   // bf16 1.0

    const int ts = t & 255;                     // staging index within the half
    const int srow = ts >> 2, scol = (ts & 3) * 16;
    const ushort* kP = kbuf + (long)(b * 2048 + h2 * 1024 + srow) * 1024 + h * 64 + scol;
    const ushort* vP = vt + (long)(bh * 64 + srow) * 2048 + h2 * 1024 + scol;

    floatx16 o[2] = {};       // O^T acc per d-tile, C-layout (row=d, col=q); UNNORMALIZED
    floatx16 lacc = {};       // ones^T · P^T : every reg = column-sum for q=m32

    // register prefetch buffers for the staging tile (16 VGPRs)
    uint4 kr0, kr1, vr0, vr1;

    // tile 0 (of this half) -> buf0
    kr0 = *(const uint4*)kP;  kr1 = *(const uint4*)(kP + 8);
    vr0 = *(const uint4*)vP;  vr1 = *(const uint4*)(vP + 8);
    {
        ushort* Ks = SM[h2][0][0]; ushort* Vs = SM[h2][0][1];
        *(uint4*)&Ks[srow * 72 + scol]     = kr0;
        *(uint4*)&Ks[srow * 72 + scol + 8] = kr1;
        *(uint4*)&Vs[srow * 72 + scol]     = vr0;
        *(uint4*)&Vs[srow * 72 + scol + 8] = vr1;
    }
    // prefetch tile 1
    kr0 = *(const uint4*)(kP + 64 * 1024); kr1 = *(const uint4*)(kP + 64 * 1024 + 8);
    vr0 = *(const uint4*)(vP + 64);        vr1 = *(const uint4*)(vP + 64 + 8);
    __syncthreads();

    #pragma unroll 2
    for (int tt = 0; tt < 16; tt++) {
        ushort* Ks = SM[h2][tt & 1][0];
        ushort* Vs = SM[h2][tt & 1][1];

        // S^T = K·Q^T FIRST: ds_reads + MFMAs start at barrier-exit
        floatx16 s[2] = {};
        __builtin_amdgcn_s_setprio(1);
        #pragma unroll
        for (int c = 0; c < 2; c++) {
            #pragma unroll
            for (int dc = 0; dc < 4; dc++) {
                short8 kf = *(const short8*)&Ks[(c * 32 + m32) * 72 + dc * 16 + hi * 8];
                s[c] = __builtin_amdgcn_mfma_f32_32x32x16_bf16(kf, qfrag[dc], s[c], 0, 0, 0);
            }
        }
        __builtin_amdgcn_s_setprio(0);

        if (tt < 15) {
            // stage tile tt+1 into alt buffer (regs loaded one iter ago);
            // drains under the QK MFMA cluster above
            ushort* Kn = SM[h2][(tt + 1) & 1][0];
            ushort* Vn = SM[h2][(tt + 1) & 1][1];
            *(uint4*)&Kn[srow * 72 + scol]     = kr0;
            *(uint4*)&Kn[srow * 72 + scol + 8] = kr1;
            *(uint4*)&Vn[srow * 72 + scol]     = vr0;
            *(uint4*)&Vn[srow * 72 + scol + 8] = vr1;
            if (tt < 14) {   // issue loads for tile tt+2 (a full iteration of cover)
                const ushort* kp = kP + (long)(tt + 2) * 64 * 1024;
                const ushort* vp = vP + (tt + 2) * 64;
                kr0 = *(const uint4*)kp; kr1 = *(const uint4*)(kp + 8);
                vr0 = *(const uint4*)vp; vr1 = *(const uint4*)(vp + 8);
            }
        }

        // p = exp2(s); pack kv pairs to bf16 with v_cvt_pk_bf16_f32
        uint pk[2][8];
        #pragma unroll
        for (int c = 0; c < 2; c++) {
            #pragma unroll
            for (int i = 0; i < 8; i++) {
                float p0 = __builtin_amdgcn_exp2f(s[c][2 * i]);
                float p1 = __builtin_amdgcn_exp2f(s[c][2 * i + 1]);
                pk[c][i] = cvt_pk_bf16(p0, p1);
            }
        }

        // O^T += V^T · P^T ; lacc += ones · P^T. B-frag (c,kc): one permlane32_swap
        // per reg-pair yields both cross-half words.
        __builtin_amdgcn_s_setprio(1);
        #pragma unroll
        for (int c = 0; c < 2; c++) {
            #pragma unroll
            for (int kc = 0; kc < 2; kc++) {
                uint a0 = pk[c][4 * kc + 0], b0 = pk[c][4 * kc + 2];
                asm("v_permlane32_swap_b32 %0, %1" : "+v"(a0), "+v"(b0));
                uint a1 = pk[c][4 * kc + 1], b1 = pk[c][4 * kc + 3];
                asm("v_permlane32_swap_b32 %0, %1" : "+v"(a1), "+v"(b1));
                union { uint u[4]; short8 s8; } cv;
                cv.u[0] = a0; cv.u[1] = a1; cv.u[2] = b0; cv.u[3] = b1;
                #pragma unroll
                for (int dt = 0; dt < 2; dt++) {
                    short8 vf = *(const short8*)&Vs[(dt * 32 + m32) * 72 + c * 32 + kc * 16 + hi * 8];
                    o[dt] = __builtin_amdgcn_mfma_f32_32x32x16_bf16(vf, cv.s8, o[dt], 0, 0, 0);
                }
                lacc = __builtin_amdgcn_mfma_f32_32x32x16_bf16(vones, cv.s8, lacc, 0, 0, 0);
            }
        }
        __builtin_amdgcn_s_setprio(0);

        __syncthreads();   // single barrier: covers RAW on buf[tt+1] and WAR on buf[tt]
    }

    // ---- combine halves through LDS: ctx = (O0 + O1) / (l0 + l1) ----
    // Loop's final barrier already separates compute reads from this reuse of SM.
    float* OL = (float*)SM;            // 4 waves x 2048 floats (32 KB)
    float* LL = OL + 4 * 2048;         // 4 waves x 64 floats
    if (h2 == 1) {
        #pragma unroll
        for (int dt = 0; dt < 2; dt++)
            #pragma unroll
            for (int i = 0; i < 16; i++)
                OL[wq * 2048 + (dt * 16 + i) * 64 + lane] = o[dt][i];
        LL[wq * 64 + lane] = lacc[0];
    }
    __syncthreads();
    if (h2 == 0) {
        float inv = 1.f / (lacc[0] + LL[wq * 64 + lane]);
        #pragma unroll
        for (int dt = 0; dt < 2; dt++) {
            #pragma unroll
            for (int i = 0; i < 16; i++) o[dt][i] += OL[wq * 2048 + (dt * 16 + i) * 64 + lane];
            #pragma unroll
            for (int g = 0; g < 4; g++) {
                ushort tmp[4] = { f2bf(o[dt][4*g+0] * inv), f2bf(o[dt][4*g+1] * inv),
                                  f2bf(o[dt][4*g+2] * inv), f2bf(o[dt][4*g+3] * inv) };
                *(uint2*)(qbuf + qrow * 1024 + h * 64 + dt * 32 + g * 8 + hi * 4) = *(uint2*)tmp;
            }
        }
    }
}

extern "C" void kernel_launch(void* const* d_in, const int* in_sizes, int n_in,
                              void* d_out, int out_size, void* d_ws, size_t ws_size,
                              hipStream_t stream) {
    const float* x     = (const float*)d_in[0];
    const float* W_qkv = (const float*)d_in[1];
    const float* b_qkv = (const float*)d_in[2];
    const float* W_out = (const float*)d_in[3];
    const float* b_out = (const float*)d_in[4];
    float* out = (float*)d_out;

    ushort* qbuf  = (ushort*)d_ws;                   // [4096][1024] 8 MB (ctx overwrites)
    ushort* kbuf  = qbuf + (size_t)4096 * 1024;      // [4096][1024] 8 MB
    ushort* vt    = kbuf + (size_t)4096 * 1024;      // [32*64][2048] 8 MB
    ushort* woutT = vt + (size_t)2048 * 2048;        // [1024][1024] 2 MB
    ushort* wqkvT = woutT + (size_t)1024 * 1024;     // [3072][1024] 6.3 MB (GEMM1 only)

    ushort* xb    = (ushort*)d_out;                  // [4096][1024] 8 MB (scratch phase)

    dim3 blk(256);
    prep_kernel<<<3072, blk, 0, stream>>>(x, W_qkv, W_out, xb, wqkvT, woutT);
    qkv_gemm_kernel<<<768, blk, 0, stream>>>(xb, wqkvT, b_qkv, qbuf, kbuf, vt);
    attn_kernel<<<512, dim3(512), 0, stream>>>(qbuf, kbuf, vt);
    out_gemm_kernel<<<512, blk, 0, stream>>>(qbuf, woutT, b_out, out);
}

// Round 10
// 177.395 us; speedup vs baseline: 1.0555x; 1.0555x over previous
//
#include <hip/hip_runtime.h>
#include <hip/hip_bf16.h>

// MHA forward. Inputs/output fp32; internal bf16 MFMA, fp32 accumulate.
// B=2 T=2048 C=1024 H=16 D=64. M=4096.
// ws (32 MB): qbuf[0,8M) bf16[4096][1024] (Q pre-scaled by 0.125*log2e; ctx overwrites)
//             kbuf[8,16M) | vt[16,24M) | woutT[24,26M) | wqkvT[26,32.3M)
// d_out as scratch until GEMM2: xb bf16 at +0.

typedef __attribute__((ext_vector_type(8)))  short short8;    // 8 bf16
typedef __attribute__((ext_vector_type(4)))  float floatx4;   // 4 fp32
typedef __attribute__((ext_vector_type(16))) float floatx16;  // 16 fp32 (32x32 acc)

__device__ inline ushort f2bf(float f) {
    union { __hip_bfloat16 h; ushort u; } c; c.h = __float2bfloat16(f); return c.u;
}

// pack two fp32 -> {lo:bf16(a), hi:bf16(b)} in one VALU op (RNE)
__device__ inline uint cvt_pk_bf16(float a, float b) {
    uint r;
    asm("v_cvt_pk_bf16_f32 %0, %1, %2" : "=v"(r) : "v"(a), "v"(b));
    return r;
}

// async global->LDS, 16B/lane; LDS dest = wave-uniform base + lane*16.
__device__ inline void gld16(const ushort* g, ushort* l) {
    __builtin_amdgcn_global_load_lds(
        (__attribute__((address_space(1))) void*)(g),
        (__attribute__((address_space(3))) void*)(l), 16, 0, 0);
}

// ---------------- fused prep: cvt_x + transpose W_qkv + transpose W_out ----------------
__device__ inline void tile_transpose(const float* __restrict__ src, ushort* __restrict__ dst,
                                      int R, int C, int rt, int ct, int t, ushort* L)
{
    const int row = t >> 2, cc = (t & 3) * 16;
    const float* sp = src + (long)(rt * 64 + row) * C + ct * 64 + cc;
    ushort tmp[16];
    #pragma unroll
    for (int i = 0; i < 4; i++) {
        float4 v = *(const float4*)(sp + i * 4);
        tmp[i*4+0]=f2bf(v.x); tmp[i*4+1]=f2bf(v.y); tmp[i*4+2]=f2bf(v.z); tmp[i*4+3]=f2bf(v.w);
    }
    *(uint4*)&L[row * 72 + cc]     = *(uint4*)&tmp[0];
    *(uint4*)&L[row * 72 + cc + 8] = *(uint4*)&tmp[8];
    __syncthreads();
    const int c = t >> 2, rc = (t & 3) * 16;
    ushort o[16];
    #pragma unroll
    for (int j = 0; j < 16; j++) o[j] = L[(rc + j) * 72 + c];
    ushort* dp = dst + (long)(ct * 64 + c) * R + rt * 64 + rc;
    *(uint4*)dp       = *(uint4*)&o[0];
    *(uint4*)(dp + 8) = *(uint4*)&o[8];
}

__global__ __launch_bounds__(256) void prep_kernel(
    const float* __restrict__ x, const float* __restrict__ Wqkv, const float* __restrict__ Wout,
    ushort* __restrict__ xb, ushort* __restrict__ wqkvT, ushort* __restrict__ woutT)
{
    __shared__ __align__(16) ushort L[64 * 72];
    const int bid = blockIdx.x, t = threadIdx.x;
    if (bid < 2048) {                                   // cvt_x
        long i = ((long)bid * 256 + t) * 8;
        float4 a = *(const float4*)(x + i);
        float4 b = *(const float4*)(x + i + 4);
        ushort tmp[8] = { f2bf(a.x), f2bf(a.y), f2bf(a.z), f2bf(a.w),
                          f2bf(b.x), f2bf(b.y), f2bf(b.z), f2bf(b.w) };
        *(uint4*)(xb + i) = *(uint4*)tmp;
    } else if (bid < 2048 + 768) {                      // W_qkv^T: 16 x 48 tiles
        int idx = bid - 2048;
        tile_transpose(Wqkv, wqkvT, 1024, 3072, idx & 15, idx >> 4, t, L);
    } else {                                            // W_out^T: 16 x 16 tiles
        int idx = bid - 2048 - 768;
        tile_transpose(Wout, woutT, 1024, 1024, idx & 15, idx >> 4, t, L);
    }
}

// ---------------- GEMM1: xb × wqkvT^T + b -> qbuf/kbuf/vt ----------------
// 2-phase pipelined staging, BK=32 (R9, passed, neutral vs R8 — kept).
// XCD supertile: 1-D grid 768, id&7 = XCD owns a 12x8 block supertile (bijective).
#define QSCALE 0.18033688011112042f   // (1/8) * log2(e), folded into Q

__global__ __launch_bounds__(256, 3) void qkv_gemm_kernel(
    const ushort* __restrict__ A, const ushort* __restrict__ Bt,
    const float* __restrict__ bias,
    ushort* __restrict__ qbuf, ushort* __restrict__ kbuf, ushort* __restrict__ vtG)
{
    __shared__ __align__(16) ushort SMEM[16384];   // phase p at p*8192: A[128][32] | B[128][32]

    const int t = threadIdx.x;
    const int w = t >> 6, lane = t & 63;
    const int r = lane & 15, qq = lane >> 4;
    const int wm = w >> 1, wn = w & 1;

    const int id = blockIdx.x;
    const int xcd = id & 7, cidx = id >> 3;        // 96 blocks per XCD
    const int lx = cidx % 12, ly = cidx / 12;      // 12 x 8 supertile
    const int bx = (xcd & 1) * 12 + lx;            // 0..23
    const int by = (xcd >> 1) * 8 + ly;            // 0..31
    const int rowBase = by * 128, colBase = bx * 128;

    // staging: wave w covers rows [w*32, w*32+32) of A and B (2 gld16 each)
    const int s_row = lane >> 2, s_k = (lane & 3) * 8;
    const ushort* aS = A  + (long)(rowBase + w * 32 + s_row) * 1024 + s_k;
    const ushort* bS = Bt + (long)(colBase + w * 32 + s_row) * 1024 + s_k;

    floatx4 acc[4][4] = {};

    // prologue: stage k-step 0 into phase 0
    gld16(aS,             SMEM + w * 1024);
    gld16(aS + 16 * 1024, SMEM + w * 1024 + 512);
    gld16(bS,             SMEM + 4096 + w * 1024);
    gld16(bS + 16 * 1024, SMEM + 4096 + w * 1024 + 512);
    __syncthreads();

    #pragma unroll 2
    for (int k = 0; k < 32; k++) {
        ushort* cur = SMEM + (k & 1) * 8192;
        if (k < 31) {               // stage k+1 into the alternate phase buffer
            ushort* nxt = SMEM + ((k + 1) & 1) * 8192;
            const int ko = (k + 1) * 32;
            gld16(aS + ko,             nxt + w * 1024);
            gld16(aS + ko + 16 * 1024, nxt + w * 1024 + 512);
            gld16(bS + ko,             nxt + 4096 + w * 1024);
            gld16(bS + ko + 16 * 1024, nxt + 4096 + w * 1024 + 512);
        }
        short8 af[4], bf4[4];
        #pragma unroll
        for (int tm = 0; tm < 4; tm++) af[tm]  = *(const short8*)&cur[(wm * 64 + tm * 16 + r) * 32 + qq * 8];
        #pragma unroll
        for (int tn = 0; tn < 4; tn++) bf4[tn] = *(const short8*)&cur[4096 + (wn * 64 + tn * 16 + r) * 32 + qq * 8];
        #pragma unroll
        for (int tm = 0; tm < 4; tm++)
            #pragma unroll
            for (int tn = 0; tn < 4; tn++)
                acc[tm][tn] = __builtin_amdgcn_mfma_f32_16x16x32_bf16(af[tm], bf4[tn], acc[tm][tn], 0, 0, 0);
        __syncthreads();            // publishes stage(k+1); WAR on cur safe (next write is k+2)
    }

    if (colBase < 2048) {
        // Q / K columns: row-major coalesced store (Q pre-scaled by QSCALE)
        #pragma unroll
        for (int tn = 0; tn < 4; tn++) {
            int col = colBase + wn * 64 + tn * 16 + r;
            float bvv = bias[col];
            #pragma unroll
            for (int tm = 0; tm < 4; tm++) {
                #pragma unroll
                for (int reg = 0; reg < 4; reg++) {
                    int row = rowBase + wm * 64 + tm * 16 + qq * 4 + reg;
                    float val = acc[tm][tn][reg] + bvv;
                    if (colBase < 1024) qbuf[(long)row * 1024 + col]        = f2bf(val * QSCALE);
                    else                kbuf[(long)row * 1024 + col - 1024] = f2bf(val);
                }
            }
        }
    } else {
        // V columns: transpose 128(t) x 64(d) per head-half through LDS -> vt[bh*64+d][t]
        ushort* L = SMEM;   // 64 x 136 scratch (8704 ushorts <= 16384)
        #pragma unroll
        for (int hh = 0; hh < 2; hh++) {
            __syncthreads();
            if (wn == hh) {
                #pragma unroll
                for (int tn = 0; tn < 4; tn++) {
                    int vc = tn * 16 + r;
                    float bvv = bias[colBase + wn * 64 + vc];
                    #pragma unroll
                    for (int tm = 0; tm < 4; tm++) {
                        int row0 = wm * 64 + tm * 16 + qq * 4;
                        ushort q4[4] = { f2bf(acc[tm][tn][0] + bvv), f2bf(acc[tm][tn][1] + bvv),
                                         f2bf(acc[tm][tn][2] + bvv), f2bf(acc[tm][tn][3] + bvv) };
                        *(uint2*)&L[vc * 136 + row0] = *(uint2*)q4;
                    }
                }
            }
            __syncthreads();
            int d = t >> 2, tq = (t & 3) * 32;
            int h_loc = ((colBase - 2048) >> 6) + hh;
            long vtrow = (long)((rowBase >> 11) * 16 + h_loc) * 64 + d;
            ushort* dst = vtG + vtrow * 2048 + (rowBase & 2047) + tq;
            #pragma unroll
            for (int i = 0; i < 4; i++)
                *(uint4*)(dst + 8 * i) = *(uint4*)&L[d * 136 + tq + 8 * i];
        }
    }
}

// ---------------- GEMM2: ctx × woutT^T + b -> fp32 out ----------------
// 2-phase BK=32 pipeline (R9, passed, kept).
// XCD supertile: 1-D grid 512, id&7 = XCD owns an 8x8 block supertile (bijective).
__global__ __launch_bounds__(256) void out_gemm_kernel(
    const ushort* __restrict__ A, const ushort* __restrict__ Bt,
    const float* __restrict__ bias, float* __restrict__ out)
{
    __shared__ __align__(16) ushort SMEM[12288];   // phase p at p*6144: A[128][32] | B[64][32]

    const int t = threadIdx.x;
    const int w = t >> 6, lane = t & 63;
    const int r = lane & 15, qq = lane >> 4;
    const int wm = w >> 1, wn = w & 1;

    const int id = blockIdx.x;
    const int xcd = id & 7, cidx = id >> 3;        // 64 blocks per XCD
    const int bx = (xcd & 1) * 8 + (cidx & 7);     // 0..15
    const int by = (xcd >> 1) * 8 + (cidx >> 3);   // 0..31
    const int rowBase = by * 128, colBase = bx * 64;

    const int s_row = lane >> 2, s_k = (lane & 3) * 8;
    const ushort* aS = A  + (long)(rowBase + w * 32 + s_row) * 1024 + s_k;
    const ushort* bS = Bt + (long)(colBase + w * 16 + s_row) * 1024 + s_k;

    floatx4 acc[4][2] = {};

    // prologue: stage k-step 0 into phase 0
    gld16(aS,             SMEM + w * 1024);
    gld16(aS + 16 * 1024, SMEM + w * 1024 + 512);
    gld16(bS,             SMEM + 4096 + w * 512);
    __syncthreads();

    #pragma unroll 2
    for (int k = 0; k < 32; k++) {
        ushort* cur = SMEM + (k & 1) * 6144;
        if (k < 31) {
            ushort* nxt = SMEM + ((k + 1) & 1) * 6144;
            const int ko = (k + 1) * 32;
            gld16(aS + ko,             nxt + w * 1024);
            gld16(aS + ko + 16 * 1024, nxt + w * 1024 + 512);
            gld16(bS + ko,             nxt + 4096 + w * 512);
        }
        short8 af[4], bf2[2];
        #pragma unroll
        for (int tm = 0; tm < 4; tm++) af[tm]  = *(const short8*)&cur[(wm * 64 + tm * 16 + r) * 32 + qq * 8];
        #pragma unroll
        for (int tn = 0; tn < 2; tn++) bf2[tn] = *(const short8*)&cur[4096 + (wn * 32 + tn * 16 + r) * 32 + qq * 8];
        #pragma unroll
        for (int tm = 0; tm < 4; tm++)
            #pragma unroll
            for (int tn = 0; tn < 2; tn++)
                acc[tm][tn] = __builtin_amdgcn_mfma_f32_16x16x32_bf16(af[tm], bf2[tn], acc[tm][tn], 0, 0, 0);
        __syncthreads();
    }

    #pragma unroll
    for (int tn = 0; tn < 2; tn++) {
        int col = colBase + wn * 32 + tn * 16 + r;
        float bvv = bias[col];
        #pragma unroll
        for (int tm = 0; tm < 4; tm++) {
            #pragma unroll
            for (int reg = 0; reg < 4; reg++) {
                int row = rowBase + wm * 64 + tm * 16 + qq * 4 + reg;
                out[(long)row * 1024 + col] = acc[tm][tn][reg] + bvv;
            }
        }
    }
}

// ---------------- MFMA flash attention, 32x32x16, transposed, BQ=256 ----------------
// 512-thread blocks, 8 waves; each wave owns 32 q (8x32 = BQ=256); ALL waves
// share ONE double-buffered K/V stream of 32 tiles (36.9 KB LDS). vs the
// previous BQ=128 h2-split: staging per thread per tile HALVES (1 uint4 K +
// 1 uint4 V), KV HBM reads halve (each tile staged once per 256 q), barriers
// per FLOP halve, and the h2-combine epilogue disappears (each wave sees all
// 32 KV tiles -> R0's direct write). Per-wave math is verbatim the passing
// R8 inner loop: QK-first at barrier-exit, permlane32_swap PV B-frag,
// ones-MFMA lacc, plain exp2 (no running max).
__global__ __launch_bounds__(512, 2) void attn_kernel(
    ushort* __restrict__ qbuf, const ushort* __restrict__ kbuf,
    const ushort* __restrict__ vt)
{
    __shared__ __align__(16) ushort SM[2][2][64 * 72];   // [buf][K|V] = 36.9 KB

    const int t = threadIdx.x;
    const int w = t >> 6, lane = t & 63;
    const int m32 = lane & 31, hi = lane >> 5;

    // XCD-aware decode: 256 blocks = 8 qt x 32 bh; id&7 = XCD gets 4 whole
    // (b,h) groups (K+V 2 MB, L2-resident across all 8 qt).
    const int id = blockIdx.x;
    const int j = id >> 3;                      // 0..31
    const int bh = (id & 7) * 4 + (j >> 3);     // 0..31
    const int qt = j & 7;                       // 0..7 (BQ = 256; wave owns 32 q)
    const int b = bh >> 4, h = bh & 15;
    const long qrow = (long)(b * 2048 + qt * 256 + w * 32 + m32);

    short8 qfrag[4];
    #pragma unroll
    for (int dc = 0; dc < 4; dc++)
        qfrag[dc] = *(const short8*)(qbuf + qrow * 1024 + h * 64 + dc * 16 + hi * 8);

    short8 vones;
    #pragma unroll
    for (int i = 0; i < 8; i++) vones[i] = (short)0x3F80;   // bf16 1.0

    // staging: 512 threads cover one 64x64 tile of K and of V (16 B each)
    const int srow = t >> 3, scol = (t & 7) * 8;
    const ushort* kP = kbuf + (long)(b * 2048 + srow) * 1024 + h * 64 + scol;
    const ushort* vP = vt + (long)(bh * 64 + srow) * 2048 + scol;

    floatx16 o[2] = {};       // O^T acc per d-tile, C-layout (row=d, col=q); unnormalized
    floatx16 lacc = {};       // ones^T · P^T : every reg = column-sum for q=m32

    // register prefetch buffers (8 VGPRs)
    uint4 kr0, vr0;

    // tile 0 -> buf0
    kr0 = *(const uint4*)kP;
    vr0 = *(const uint4*)vP;
    *(uint4*)&SM[0][0][srow * 72 + scol] = kr0;
    *(uint4*)&SM[0][1][srow * 72 + scol] = vr0;
    // prefetch tile 1
    kr0 = *(const uint4*)(kP + 64 * 1024);
    vr0 = *(const uint4*)(vP + 64);
    __syncthreads();

    #pragma unroll 2
    for (int tt = 0; tt < 32; tt++) {
        ushort* Ks = SM[tt & 1][0];
        ushort* Vs = SM[tt & 1][1];

        // S^T = K·Q^T FIRST: ds_reads + MFMAs start at barrier-exit
        floatx16 s[2] = {};
        __builtin_amdgcn_s_setprio(1);
        #pragma unroll
        for (int c = 0; c < 2; c++) {
            #pragma unroll
            for (int dc = 0; dc < 4; dc++) {
                short8 kf = *(const short8*)&Ks[(c * 32 + m32) * 72 + dc * 16 + hi * 8];
                s[c] = __builtin_amdgcn_mfma_f32_32x32x16_bf16(kf, qfrag[dc], s[c], 0, 0, 0);
            }
        }
        __builtin_amdgcn_s_setprio(0);

        if (tt < 31) {
            // stage tile tt+1 into alt buffer (regs loaded one iter ago);
            // drains under the QK MFMA cluster above
            *(uint4*)&SM[(tt + 1) & 1][0][srow * 72 + scol] = kr0;
            *(uint4*)&SM[(tt + 1) & 1][1][srow * 72 + scol] = vr0;
            if (tt < 30) {   // issue loads for tile tt+2 (a full iteration of cover)
                kr0 = *(const uint4*)(kP + (long)(tt + 2) * 64 * 1024);
                vr0 = *(const uint4*)(vP + (tt + 2) * 64);
            }
        }

        // p = exp2(s); pack kv pairs to bf16 with v_cvt_pk_bf16_f32
        uint pk[2][8];
        #pragma unroll
        for (int c = 0; c < 2; c++) {
            #pragma unroll
            for (int i = 0; i < 8; i++) {
                float p0 = __builtin_amdgcn_exp2f(s[c][2 * i]);
                float p1 = __builtin_amdgcn_exp2f(s[c][2 * i + 1]);
                pk[c][i] = cvt_pk_bf16(p0, p1);
            }
        }

        // O^T += V^T · P^T ; lacc += ones · P^T. B-frag (c,kc): one permlane32_swap
        // per reg-pair yields both cross-half words.
        __builtin_amdgcn_s_setprio(1);
        #pragma unroll
        for (int c = 0; c < 2; c++) {
            #pragma unroll
            for (int kc = 0; kc < 2; kc++) {
                uint a0 = pk[c][4 * kc + 0], b0 = pk[c][4 * kc + 2];
                asm("v_permlane32_swap_b32 %0, %1" : "+v"(a0), "+v"(b0));
                uint a1 = pk[c][4 * kc + 1], b1 = pk[c][4 * kc + 3];
                asm("v_permlane32_swap_b32 %0, %1" : "+v"(a1), "+v"(b1));
                union { uint u[4]; short8 s8; } cv;
                cv.u[0] = a0; cv.u[1] = a1; cv.u[2] = b0; cv.u[3] = b1;
                #pragma unroll
                for (int dt = 0; dt < 2; dt++) {
                    short8 vf = *(const short8*)&Vs[(dt * 32 + m32) * 72 + c * 32 + kc * 16 + hi * 8];
                    o[dt] = __builtin_amdgcn_mfma_f32_32x32x16_bf16(vf, cv.s8, o[dt], 0, 0, 0);
                }
                lacc = __builtin_amdgcn_mfma_f32_32x32x16_bf16(vones, cv.s8, lacc, 0, 0, 0);
            }
        }
        __builtin_amdgcn_s_setprio(0);

        __syncthreads();   // single barrier: covers RAW on buf[tt+1] and WAR on buf[tt]
    }

    // every lacc reg holds the full 2048-kv column sum for q=m32 (both hi halves)
    float inv = 1.f / lacc[0];

    // write ctx = O^T/l into the consumed Q slice: regs 4g..4g+3 = consecutive d
    #pragma unroll
    for (int dt = 0; dt < 2; dt++) {
        #pragma unroll
        for (int g = 0; g < 4; g++) {
            ushort tmp[4] = { f2bf(o[dt][4*g+0] * inv), f2bf(o[dt][4*g+1] * inv),
                              f2bf(o[dt][4*g+2] * inv), f2bf(o[dt][4*g+3] * inv) };
            *(uint2*)(qbuf + qrow * 1024 + h * 64 + dt * 32 + g * 8 + hi * 4) = *(uint2*)tmp;
        }
    }
}

extern "C" void kernel_launch(void* const* d_in, const int* in_sizes, int n_in,
                              void* d_out, int out_size, void* d_ws, size_t ws_size,
                              hipStream_t stream) {
    const float* x     = (const float*)d_in[0];
    const float* W_qkv = (const float*)d_in[1];
    const float* b_qkv = (const float*)d_in[2];
    const float* W_out = (const float*)d_in[3];
    const float* b_out = (const float*)d_in[4];
    float* out = (float*)d_out;

    ushort* qbuf  = (ushort*)d_ws;                   // [4096][1024] 8 MB (ctx overwrites)
    ushort* kbuf  = qbuf + (size_t)4096 * 1024;      // [4096][1024] 8 MB
    ushort* vt    = kbuf + (size_t)4096 * 1024;      // [32*64][2048] 8 MB
    ushort* woutT = vt + (size_t)2048 * 2048;        // [1024][1024] 2 MB
    ushort* wqkvT = woutT + (size_t)1024 * 1024;     // [3072][1024] 6.3 MB (GEMM1 only)

    ushort* xb    = (ushort*)d_out;                  // [4096][1024] 8 MB (scratch phase)

    dim3 blk(256);
    prep_kernel<<<3072, blk, 0, stream>>>(x, W_qkv, W_out, xb, wqkvT, woutT);
    qkv_gemm_kernel<<<768, blk, 0, stream>>>(xb, wqkvT, b_qkv, qbuf, kbuf, vt);
    attn_kernel<<<256, dim3(512), 0, stream>>>(qbuf, kbuf, vt);
    out_gemm_kernel<<<512, blk, 0, stream>>>(qbuf, woutT, b_out, out);
}